// Round 2
// baseline (496.199 us; speedup 1.0000x reference)
//
#include <hip/hip_runtime.h>
#include <math.h>

#define NS 131072
#define DIM 256
#define CHUNK 512
#define WARM 128

// DPP-based butterfly add (stays on VALU pipe, no DS traffic)
template<int CTRL>
__device__ __forceinline__ float dpp_add(float x) {
    int y = __builtin_amdgcn_update_dpp(0, __float_as_int(x), CTRL, 0xf, 0xf, true);
    return x + __int_as_float(y);
}

// Pass 1: parallel-in-time HMM forward. 256 blocks; block c computes output
// steps [512c, 512c+512) after a 128-step warmup from a uniform guess
// (projective contraction of diag(ps)*T makes warmup converge below fp32
// noise). Unnormalized recursion v <- (256*diag(ps_s)*T) @ v; pass 2
// normalizes.
//
// 1024 threads = 16 waves/block, 1 block/CU -> 4 waves/SIMD for latency
// hiding. Thread t owns T rows [4g,4g+4) x cols [16*c16,16*c16+16)
// (64 VGPRs), c16 = t&15, g = t>>4.
__global__ __launch_bounds__(1024, 4) void hmm_pass1(
        const float* __restrict__ ps, const float* __restrict__ Tm,
        const float* __restrict__ state0, float* __restrict__ out) {
    __shared__ __align__(16) float sm[2][DIM];

    const int t   = threadIdx.x;
    const int c16 = t & 15;    // column-chunk: cols [16*c16, 16*c16+16)
    const int g   = t >> 4;    // bin group: bins [4g, 4g+4)
    const int blk = blockIdx.x;

    // 4x16 tile of T, scaled by 256, segment order rotated per-lane
    // (seg = (r+c16)&3) so each step's 16 distinct LDS float4 reads tile
    // the 256B state slice exactly once -> 2-way bank aliasing (free).
    float4 Tr[4][4];
    #pragma unroll
    for (int r = 0; r < 4; ++r) {
        const int col = 16 * c16 + 4 * ((r + c16) & 3);
        #pragma unroll
        for (int b = 0; b < 4; ++b) {
            float4 v = *reinterpret_cast<const float4*>(
                Tm + (size_t)(4 * g + b) * DIM + col);
            v.x *= 256.f; v.y *= 256.f; v.z *= 256.f; v.w *= 256.f;
            Tr[r][b] = v;
        }
    }

    if (t < DIM) sm[0][t] = (blk == 0) ? state0[t] : 1.0f;
    __syncthreads();

    const int sOut   = blk * CHUNK;
    const int sStart = (blk == 0) ? 0 : (sOut - WARM);
    const int sEnd   = sOut + CHUNK;

    float4 psc = *reinterpret_cast<const float4*>(
        ps + (size_t)sStart * DIM + 4 * g);

    auto do_step = [&](int s, int B) {
        // prefetch next step's ps row (clamped at the end)
        const size_t sn = (s + 1 < NS) ? (size_t)(s + 1) : (size_t)(NS - 1);
        float4 psn = *reinterpret_cast<const float4*>(ps + sn * DIM + 4 * g);

        float a0 = 0.f, a1 = 0.f, a2 = 0.f, a3 = 0.f;
        const float* sb = sm[B];
        #pragma unroll
        for (int r = 0; r < 4; ++r) {
            float4 sv = *reinterpret_cast<const float4*>(
                sb + 16 * c16 + 4 * ((r + c16) & 3));
            a0 = fmaf(Tr[r][0].x, sv.x, a0); a0 = fmaf(Tr[r][0].y, sv.y, a0);
            a0 = fmaf(Tr[r][0].z, sv.z, a0); a0 = fmaf(Tr[r][0].w, sv.w, a0);
            a1 = fmaf(Tr[r][1].x, sv.x, a1); a1 = fmaf(Tr[r][1].y, sv.y, a1);
            a1 = fmaf(Tr[r][1].z, sv.z, a1); a1 = fmaf(Tr[r][1].w, sv.w, a1);
            a2 = fmaf(Tr[r][2].x, sv.x, a2); a2 = fmaf(Tr[r][2].y, sv.y, a2);
            a2 = fmaf(Tr[r][2].z, sv.z, a2); a2 = fmaf(Tr[r][2].w, sv.w, a2);
            a3 = fmaf(Tr[r][3].x, sv.x, a3); a3 = fmaf(Tr[r][3].y, sv.y, a3);
            a3 = fmaf(Tr[r][3].z, sv.z, a3); a3 = fmaf(Tr[r][3].w, sv.w, a3);
        }

        // butterfly over 16 column-chunk lanes: xor1 (quad_perm 0xB1),
        // xor2 (quad_perm 0x4E), then half-mirror/mirror (valid because
        // values are quad-/octet-uniform by then).
        a0 = dpp_add<0xB1>(a0); a0 = dpp_add<0x4E>(a0);
        a0 = dpp_add<0x141>(a0); a0 = dpp_add<0x140>(a0);
        a1 = dpp_add<0xB1>(a1); a1 = dpp_add<0x4E>(a1);
        a1 = dpp_add<0x141>(a1); a1 = dpp_add<0x140>(a1);
        a2 = dpp_add<0xB1>(a2); a2 = dpp_add<0x4E>(a2);
        a2 = dpp_add<0x141>(a2); a2 = dpp_add<0x140>(a2);
        a3 = dpp_add<0xB1>(a3); a3 = dpp_add<0x4E>(a3);
        a3 = dpp_add<0x141>(a3); a3 = dpp_add<0x140>(a3);

        float4 pn;
        pn.x = a0 * psc.x; pn.y = a1 * psc.y;
        pn.z = a2 * psc.z; pn.w = a3 * psc.w;

        if (c16 == 0) {
            *reinterpret_cast<float4*>(&sm[B ^ 1][4 * g]) = pn;
            if (s >= sOut) {
                *reinterpret_cast<float4*>(out + (size_t)s * DIM + 4 * g) = pn;
            }
        }

        // raw barrier: drain LDS only -- ps prefetch and out stores stay
        // in flight across the barrier (no vmcnt(0)).
        asm volatile("s_waitcnt lgkmcnt(0)" ::: "memory");
        __builtin_amdgcn_s_barrier();
        asm volatile("" ::: "memory");

        psc = psn;
    };

    // step counts are even for every block (512 or 640) -> unroll x2 with
    // compile-time LDS buffer selection.
    for (int s = sStart; s < sEnd; s += 2) {
        do_step(s, 0);
        do_step(s + 1, 1);
    }
}

// Pass 2: one wave per row. Normalize v in place, compute std.
__global__ __launch_bounds__(256) void hmm_pass2(float* __restrict__ out) {
    const int lane = threadIdx.x & 63;
    const int wid  = blockIdx.x * (blockDim.x >> 6) + (threadIdx.x >> 6);
    const int nw   = gridDim.x * (blockDim.x >> 6);
    float* stdv = out + (size_t)NS * DIM;

    for (int row = wid; row < NS; row += nw) {
        float4 v = *reinterpret_cast<float4*>(out + (size_t)row * DIM + 4 * lane);
        const float j0 = (float)(4 * lane);
        const float b0 = 30.f + 0.703125f * j0;
        const float b1 = 30.f + 0.703125f * (j0 + 1.f);
        const float b2 = 30.f + 0.703125f * (j0 + 2.f);
        const float b3 = 30.f + 0.703125f * (j0 + 3.f);

        float sS = v.x + v.y + v.z + v.w;
        float e1 = v.x * b0 + v.y * b1 + v.z * b2 + v.w * b3;
        float e2 = v.x * b0 * b0 + v.y * b1 * b1 + v.z * b2 * b2 + v.w * b3 * b3;

        #pragma unroll
        for (int k = 1; k < 64; k <<= 1) {
            sS += __shfl_xor(sS, k);
            e1 += __shfl_xor(e1, k);
            e2 += __shfl_xor(e2, k);
        }

        const float inv = 1.f / sS;
        v.x *= inv; v.y *= inv; v.z *= inv; v.w *= inv;
        *reinterpret_cast<float4*>(out + (size_t)row * DIM + 4 * lane) = v;

        if (lane == 0) {
            const float m   = e1 * inv;
            const float var = e2 * inv - m * m;
            stdv[row] = sqrtf(var > 0.f ? var : 0.f);
        }
    }
}

extern "C" void kernel_launch(void* const* d_in, const int* in_sizes, int n_in,
                              void* d_out, int out_size, void* d_ws, size_t ws_size,
                              hipStream_t stream) {
    const float* ps     = (const float*)d_in[0];
    const float* Tm     = (const float*)d_in[1];
    const float* state0 = (const float*)d_in[2];
    float* out = (float*)d_out;

    hmm_pass1<<<dim3(NS / CHUNK), dim3(1024), 0, stream>>>(ps, Tm, state0, out);
    hmm_pass2<<<dim3(2048), dim3(256), 0, stream>>>(out);
}

// Round 3
// 431.341 us; speedup vs baseline: 1.1504x; 1.1504x over previous
//
#include <hip/hip_runtime.h>
#include <math.h>

#define NS 131072
#define DIM 256
#define CHUNK 512
#define WARM 64

typedef float v2f __attribute__((ext_vector_type(2)));

// DPP-based butterfly add (stays on VALU pipe, no DS traffic)
template<int CTRL>
__device__ __forceinline__ float dpp_add(float x) {
    int y = __builtin_amdgcn_update_dpp(0, __float_as_int(x), CTRL, 0xf, 0xf, true);
    return x + __int_as_float(y);
}

// Pin a float4 into VGPRs: the asm may "modify" the values, so the compiler
// can neither rematerialize the originating global load nor fold it away.
#define PIN4(v) asm volatile("" : "+v"((v).x), "+v"((v).y), "+v"((v).z), "+v"((v).w))

// Pass 1: parallel-in-time HMM forward. 256 blocks; block c computes output
// steps [512c, 512c+512) after a 64-step warmup from a uniform guess
// (projective contraction of diag(ps)*T converges far below fp32 noise).
// Unnormalized recursion v <- (256*diag(ps_s)*T) @ v; pass 2 normalizes.
//
// 512 threads = 8 waves, 1 block/CU. Thread t: c16 = t&15 (cols
// [16c16,16c16+16)), g = t>>4 (rows [8g,8g+8)). Tile = 8x16 = 128 VGPRs,
// pinned. Per step: 4 ds_read_b128 (bank-conflict-free via
// seg=(r+(c16>>1))&3 rotation), 64 packed FMAs, 4-stage DPP butterfly.
__global__ __launch_bounds__(512, 2) void hmm_pass1(
        const float* __restrict__ ps, const float* __restrict__ Tm,
        const float* __restrict__ state0, float* __restrict__ out) {
    __shared__ __align__(16) float sm[2][DIM];

    const int t   = threadIdx.x;
    const int c16 = t & 15;
    const int g   = t >> 4;            // rows [8g, 8g+8)
    const int rot = (c16 >> 1) & 3;
    const int blk = blockIdx.x;

    // Tile load, scaled by 256, segment order rotated so the per-step LDS
    // reads hit each bank-quad exactly twice (2-way = free).
    float4 Tr[8][4];
    #pragma unroll
    for (int i = 0; i < 8; ++i) {
        #pragma unroll
        for (int r = 0; r < 4; ++r) {
            const int col = 16 * c16 + 4 * ((r + rot) & 3);
            float4 v = *reinterpret_cast<const float4*>(
                Tm + (size_t)(8 * g + i) * DIM + col);
            v.x *= 256.f; v.y *= 256.f; v.z *= 256.f; v.w *= 256.f;
            PIN4(v);
            Tr[i][r] = v;
        }
    }

    // per-lane LDS byte offsets for the 4 swizzled reads
    const int a0 = 64 * c16 + 16 * ((0 + rot) & 3);
    const int a1 = 64 * c16 + 16 * ((1 + rot) & 3);
    const int a2 = 64 * c16 + 16 * ((2 + rot) & 3);
    const int a3 = 64 * c16 + 16 * ((3 + rot) & 3);

    if (t < DIM) sm[0][t] = (blk == 0) ? state0[t] : 1.0f;
    __syncthreads();

    const int sOut   = blk * CHUNK;
    const int sStart = (blk == 0) ? 0 : (sOut - WARM);
    const int sEnd   = sOut + CHUNK;

    float4 psc0 = *reinterpret_cast<const float4*>(ps + (size_t)sStart * DIM + 8 * g);
    float4 psc1 = *reinterpret_cast<const float4*>(ps + (size_t)sStart * DIM + 8 * g + 4);

    auto do_step = [&](int s, int B) {
        const size_t sn = (s + 1 < NS) ? (size_t)(s + 1) : (size_t)(NS - 1);
        float4 q0 = *reinterpret_cast<const float4*>(ps + sn * DIM + 8 * g);
        float4 q1 = *reinterpret_cast<const float4*>(ps + sn * DIM + 8 * g + 4);

        const char* sb = reinterpret_cast<const char*>(sm) + B * 1024;
        float4 s0 = *reinterpret_cast<const float4*>(sb + a0);
        float4 s1 = *reinterpret_cast<const float4*>(sb + a1);
        float4 s2 = *reinterpret_cast<const float4*>(sb + a2);
        float4 s3 = *reinterpret_cast<const float4*>(sb + a3);

        v2f sv[8];
        sv[0] = v2f{s0.x, s0.y}; sv[1] = v2f{s0.z, s0.w};
        sv[2] = v2f{s1.x, s1.y}; sv[3] = v2f{s1.z, s1.w};
        sv[4] = v2f{s2.x, s2.y}; sv[5] = v2f{s2.z, s2.w};
        sv[6] = v2f{s3.x, s3.y}; sv[7] = v2f{s3.z, s3.w};

        v2f acc[8];
        #pragma unroll
        for (int i = 0; i < 8; ++i) acc[i] = v2f{0.f, 0.f};
        #pragma unroll
        for (int i = 0; i < 8; ++i) {
            #pragma unroll
            for (int r = 0; r < 4; ++r) {
                const v2f* tp = reinterpret_cast<const v2f*>(&Tr[i][r]);
                acc[i] = __builtin_elementwise_fma(tp[0], sv[2 * r],     acc[i]);
                acc[i] = __builtin_elementwise_fma(tp[1], sv[2 * r + 1], acc[i]);
            }
        }

        float a[8];
        #pragma unroll
        for (int i = 0; i < 8; ++i) {
            float x = acc[i].x + acc[i].y;
            // butterfly over 16 column-chunk lanes:
            // xor1 (quad_perm 0xB1), xor2 (quad_perm 0x4E),
            // half-mirror (==xor4 once quad-uniform), mirror (==xor8).
            x = dpp_add<0xB1>(x); x = dpp_add<0x4E>(x);
            x = dpp_add<0x141>(x); x = dpp_add<0x140>(x);
            a[i] = x;
        }

        float4 pn0, pn1;
        pn0.x = a[0] * psc0.x; pn0.y = a[1] * psc0.y;
        pn0.z = a[2] * psc0.z; pn0.w = a[3] * psc0.w;
        pn1.x = a[4] * psc1.x; pn1.y = a[5] * psc1.y;
        pn1.z = a[6] * psc1.z; pn1.w = a[7] * psc1.w;

        if (c16 < 2) {
            float4 pw;
            pw.x = c16 ? pn1.x : pn0.x; pw.y = c16 ? pn1.y : pn0.y;
            pw.z = c16 ? pn1.z : pn0.z; pw.w = c16 ? pn1.w : pn0.w;
            *reinterpret_cast<float4*>(
                reinterpret_cast<char*>(sm) + (B ^ 1) * 1024 + 32 * g + 16 * c16) = pw;
            if (s >= sOut) {
                *reinterpret_cast<float4*>(out + (size_t)s * DIM + 8 * g + 4 * c16) = pw;
            }
        }

        // raw barrier: drain LDS only -- ps prefetch and out stores stay
        // in flight across the barrier (no vmcnt(0)).
        asm volatile("s_waitcnt lgkmcnt(0)" ::: "memory");
        __builtin_amdgcn_s_barrier();
        asm volatile("" ::: "memory");

        psc0 = q0; psc1 = q1;
    };

    // step counts are even for every block (512 or 576) -> unroll x2 with
    // compile-time LDS buffer selection.
    for (int s = sStart; s < sEnd; s += 2) {
        do_step(s, 0);
        do_step(s + 1, 1);
    }
}

// Pass 2: one wave per row. Normalize v in place, compute std.
__global__ __launch_bounds__(256) void hmm_pass2(float* __restrict__ out) {
    const int lane = threadIdx.x & 63;
    const int wid  = blockIdx.x * (blockDim.x >> 6) + (threadIdx.x >> 6);
    const int nw   = gridDim.x * (blockDim.x >> 6);
    float* stdv = out + (size_t)NS * DIM;

    for (int row = wid; row < NS; row += nw) {
        float4 v = *reinterpret_cast<float4*>(out + (size_t)row * DIM + 4 * lane);
        const float j0 = (float)(4 * lane);
        const float b0 = 30.f + 0.703125f * j0;
        const float b1 = 30.f + 0.703125f * (j0 + 1.f);
        const float b2 = 30.f + 0.703125f * (j0 + 2.f);
        const float b3 = 30.f + 0.703125f * (j0 + 3.f);

        float sS = v.x + v.y + v.z + v.w;
        float e1 = v.x * b0 + v.y * b1 + v.z * b2 + v.w * b3;
        float e2 = v.x * b0 * b0 + v.y * b1 * b1 + v.z * b2 * b2 + v.w * b3 * b3;

        #pragma unroll
        for (int k = 1; k < 64; k <<= 1) {
            sS += __shfl_xor(sS, k);
            e1 += __shfl_xor(e1, k);
            e2 += __shfl_xor(e2, k);
        }

        const float inv = 1.f / sS;
        v.x *= inv; v.y *= inv; v.z *= inv; v.w *= inv;
        *reinterpret_cast<float4*>(out + (size_t)row * DIM + 4 * lane) = v;

        if (lane == 0) {
            const float m   = e1 * inv;
            const float var = e2 * inv - m * m;
            stdv[row] = sqrtf(var > 0.f ? var : 0.f);
        }
    }
}

extern "C" void kernel_launch(void* const* d_in, const int* in_sizes, int n_in,
                              void* d_out, int out_size, void* d_ws, size_t ws_size,
                              hipStream_t stream) {
    const float* ps     = (const float*)d_in[0];
    const float* Tm     = (const float*)d_in[1];
    const float* state0 = (const float*)d_in[2];
    float* out = (float*)d_out;

    hmm_pass1<<<dim3(NS / CHUNK), dim3(512), 0, stream>>>(ps, Tm, state0, out);
    hmm_pass2<<<dim3(2048), dim3(256), 0, stream>>>(out);
}

// Round 4
// 131.793 us; speedup vs baseline: 3.7650x; 3.2729x over previous
//
#include <hip/hip_runtime.h>
#include <math.h>

#define NS 131072
#define DIM 256
#define NCH 16                 // chains (time-chunks) per block
#define OUTS 32                // output steps per chain
#define WARM 64                // warmup steps (projective contraction)
#define NSTEPS (WARM + OUTS)   // 96

typedef short bf16x8 __attribute__((ext_vector_type(8)));
typedef short bf16x4 __attribute__((ext_vector_type(4)));
typedef float f32x4  __attribute__((ext_vector_type(4)));

__device__ __forceinline__ unsigned short f2bf(float x) {  // RTE f32->bf16
    unsigned u = __float_as_uint(x);
    return (unsigned short)((u + 0x7FFFu + ((u >> 16) & 1u)) >> 16);
}
__device__ __forceinline__ float bf2f(unsigned short h) {
    return __uint_as_float(((unsigned)h) << 16);
}

// Parallel-in-time HMM forward via MFMA.
// 256 blocks x 16 chains; chain = one 32-step output chunk + 64-step warmup
// from a uniform guess (diag(ps)*T is a projective contraction; 64 random
// steps converge far below fp32 noise; chain 0 is re-seeded with state0).
// Per block-step: S_new = ps_row ⊙ (256*T @ S), T as bf16 hi+lo (2 MFMAs),
// S as bf16 in swizzled LDS, accum fp32. Normalization + std are computed
// in-kernel per output step (no second pass over the 134 MB output).
__global__ void __launch_bounds__(512)
__attribute__((amdgpu_waves_per_eu(2, 2)))
hmm_mfma(const float* __restrict__ ps, const float* __restrict__ Tm,
         const float* __restrict__ state0, float* __restrict__ out) {
    __shared__ __align__(16) unsigned short Sbuf[2][NCH][DIM]; // bf16 states, XOR-swizzled rows
    __shared__ __align__(16) float red[NCH][28];               // partials [chain][{s,e1,e2}*8 + wave]
    __shared__ __align__(16) float tot[NCH][4];                // {sum, e1, e2, pad}

    const int t    = threadIdx.x;
    const int lane = t & 63;
    const int wid  = t >> 6;      // wave 0..7, owns bins [32*wid, 32*wid+32)
    const int col  = lane & 15;   // chain / N-col (and A-row index)
    const int lq   = lane >> 4;   // k-group / C-row group
    const int blk  = blockIdx.x;
    const int binb = wid * 32;

    // ---- A-frags: T (x256) as bf16 hi/lo, resident in VGPRs (32 x 16B) ----
    bf16x8 Ah[2][8], Al[2][8];
    #pragma unroll
    for (int m = 0; m < 2; ++m) {
        const size_t row = (size_t)(binb + m * 16 + col);
        #pragma unroll
        for (int ks = 0; ks < 8; ++ks) {
            const float* p = Tm + row * DIM + ks * 32 + lq * 8;
            f32x4 u0 = *(const f32x4*)p;
            f32x4 u1 = *(const f32x4*)(p + 4);
            const float f[8] = {u0.x, u0.y, u0.z, u0.w, u1.x, u1.y, u1.z, u1.w};
            bf16x8 h, l;
            #pragma unroll
            for (int e = 0; e < 8; ++e) {
                const float x = f[e] * 256.0f;
                const unsigned short hs = f2bf(x);
                h[e] = (short)hs;
                l[e] = (short)f2bf(x - bf2f(hs));
            }
            Ah[m][ks] = h; Al[m][ks] = l;
        }
    }

    // ---- init: all chains = uniform positive vector (scale-free) ----
    {
        const int ch = t >> 5, g = t & 31;
        char* p = (char*)Sbuf + ch * 512 + ((g * 16) ^ ((ch & 7) << 4));
        bf16x8 one;
        #pragma unroll
        for (int e = 0; e < 8; ++e) one[e] = (short)0x3F80;  // 1.0bf
        *(bf16x8*)p = one;
    }
    __syncthreads();

    const int sbase = (blk * NCH + col) * OUTS - WARM;  // per-lane (chain) time base
    int s0 = sbase < 0 ? 0 : sbase;
    f32x4 psc0 = *(const f32x4*)(ps + (size_t)s0 * DIM + binb + lq * 4);
    f32x4 psc1 = *(const f32x4*)(ps + (size_t)s0 * DIM + binb + 16 + lq * 4);

    const int xsw = (col & 7) << 4;  // LDS XOR-swizzle for this chain row

    for (int i = 0; i < NSTEPS; ++i) {
        const int cur = i & 1;

        if (i == WARM && blk == 0) {
            // re-seed chain 0 with the exact initial state (its warmup used
            // clamped ps[0] repeats); chain 0 swizzle is identity.
            if (t < DIM) {
                *(unsigned short*)((char*)Sbuf + cur * 8192 + 2 * t) = f2bf(state0[t]);
            }
            asm volatile("s_waitcnt lgkmcnt(0)" ::: "memory");
            __builtin_amdgcn_s_barrier();
            asm volatile("" ::: "memory");
        }

        // pin A-frags (forbid spill/remat)
        #pragma unroll
        for (int ks = 0; ks < 8; ++ks) {
            asm volatile("" : "+v"(Ah[0][ks]), "+v"(Ah[1][ks]),
                              "+v"(Al[0][ks]), "+v"(Al[1][ks]));
        }

        // B-frags: 8 swizzled ds_read_b128 (lane holds S[k..k+7][chain])
        const char* sb = (const char*)Sbuf + cur * 8192 + col * 512;
        bf16x8 Bf[8];
        #pragma unroll
        for (int ks = 0; ks < 8; ++ks)
            Bf[ks] = *(const bf16x8*)(sb + ((ks * 64 + lq * 16) ^ xsw));

        // prefetch next step's ps row segment (clamped)
        int snx = sbase + i + 1;
        snx = snx < 0 ? 0 : (snx > NS - 1 ? NS - 1 : snx);
        f32x4 pn0 = *(const f32x4*)(ps + (size_t)snx * DIM + binb + lq * 4);
        f32x4 pn1 = *(const f32x4*)(ps + (size_t)snx * DIM + binb + 16 + lq * 4);

        // 32 MFMA: acc = (T_hi + T_lo) @ S, fp32 accum
        f32x4 acc0 = {0.f, 0.f, 0.f, 0.f};
        f32x4 acc1 = {0.f, 0.f, 0.f, 0.f};
        #pragma unroll
        for (int ks = 0; ks < 8; ++ks) {
            acc0 = __builtin_amdgcn_mfma_f32_16x16x32_bf16(Ah[0][ks], Bf[ks], acc0, 0, 0, 0);
            acc1 = __builtin_amdgcn_mfma_f32_16x16x32_bf16(Ah[1][ks], Bf[ks], acc1, 0, 0, 0);
            acc0 = __builtin_amdgcn_mfma_f32_16x16x32_bf16(Al[0][ks], Bf[ks], acc0, 0, 0, 0);
            acc1 = __builtin_amdgcn_mfma_f32_16x16x32_bf16(Al[1][ks], Bf[ks], acc1, 0, 0, 0);
        }

        const f32x4 v0 = acc0 * psc0;   // lane: bins binb+lq*4+{0..3}, chain col
        const f32x4 v1 = acc1 * psc1;   // lane: bins binb+16+lq*4+{0..3}

        // next-state bf16 write (swizzled, 2 x ds_write_b64)
        {
            char* db = (char*)Sbuf + (cur ^ 1) * 8192 + col * 512;
            bf16x4 w0, w1;
            w0[0] = (short)f2bf(v0.x); w0[1] = (short)f2bf(v0.y);
            w0[2] = (short)f2bf(v0.z); w0[3] = (short)f2bf(v0.w);
            w1[0] = (short)f2bf(v1.x); w1[1] = (short)f2bf(v1.y);
            w1[2] = (short)f2bf(v1.z); w1[3] = (short)f2bf(v1.w);
            *(bf16x4*)(db + ((binb * 2 + lq * 8) ^ xsw)) = w0;
            *(bf16x4*)(db + ((binb * 2 + 32 + lq * 8) ^ xsw)) = w1;
        }

        if (i >= WARM) {
            const int srow = sbase + i;
            // per-lane moments over its 8 bins
            const float bst = 0.703125f;               // 180/256
            const float c0 = 30.0f + bst * (float)(binb + lq * 4);
            const float fv[8] = {v0.x, v0.y, v0.z, v0.w, v1.x, v1.y, v1.z, v1.w};
            float sp = 0.f, e1 = 0.f, e2 = 0.f;
            #pragma unroll
            for (int j = 0; j < 8; ++j) {
                const float b = c0 + bst * (float)(j < 4 ? j : j + 12);
                sp += fv[j];
                const float tb = fv[j] * b;
                e1 += tb; e2 += tb * b;
            }
            // reduce over the 4 lanes sharing this chain within the wave
            sp += __shfl_xor(sp, 16); sp += __shfl_xor(sp, 32);
            e1 += __shfl_xor(e1, 16); e1 += __shfl_xor(e1, 32);
            e2 += __shfl_xor(e2, 16); e2 += __shfl_xor(e2, 32);
            if (lane < 16) {
                red[lane][wid]      = sp;
                red[lane][8 + wid]  = e1;
                red[lane][16 + wid] = e2;
            }
            asm volatile("s_waitcnt lgkmcnt(0)" ::: "memory");
            __builtin_amdgcn_s_barrier();
            asm volatile("" ::: "memory");
            if (t < 48) {  // 48 reducers: (chain, quantity)
                const int ch = t & 15, v = t >> 4;
                f32x4 a = *(const f32x4*)&red[ch][v * 8];
                f32x4 b = *(const f32x4*)&red[ch][v * 8 + 4];
                tot[ch][v] = (a.x + a.y) + (a.z + a.w) + ((b.x + b.y) + (b.z + b.w));
            }
            asm volatile("s_waitcnt lgkmcnt(0)" ::: "memory");
            __builtin_amdgcn_s_barrier();
            asm volatile("" ::: "memory");
            const float inv = 1.0f / tot[col][0];
            const f32x4 o0 = v0 * inv, o1 = v1 * inv;
            *(f32x4*)(out + (size_t)srow * DIM + binb + lq * 4) = o0;
            *(f32x4*)(out + (size_t)srow * DIM + binb + 16 + lq * 4) = o1;
            if (t < NCH) {
                const float st = tot[t][0];
                const float m1 = tot[t][1] / st, m2 = tot[t][2] / st;
                const float var = m2 - m1 * m1;
                const int sr = (blk * NCH + t) * OUTS - WARM + i;
                out[(size_t)NS * DIM + sr] = sqrtf(var > 0.f ? var : 0.f);
            }
        } else {
            asm volatile("s_waitcnt lgkmcnt(0)" ::: "memory");
            __builtin_amdgcn_s_barrier();
            asm volatile("" ::: "memory");
        }

        psc0 = pn0; psc1 = pn1;
    }
}

extern "C" void kernel_launch(void* const* d_in, const int* in_sizes, int n_in,
                              void* d_out, int out_size, void* d_ws, size_t ws_size,
                              hipStream_t stream) {
    const float* ps     = (const float*)d_in[0];
    const float* Tm     = (const float*)d_in[1];
    const float* state0 = (const float*)d_in[2];
    float* out = (float*)d_out;

    hmm_mfma<<<dim3(256), dim3(512), 0, stream>>>(ps, Tm, state0, out);
}

// Round 5
// 106.549 us; speedup vs baseline: 4.6570x; 1.2369x over previous
//
#include <hip/hip_runtime.h>
#include <math.h>

#define NS 131072
#define DIM 256
#define NCH 16                 // chains (time-chunks) per block = MFMA N
#define OUTS 32                // output steps per chain
#define WARM 32                // warmup steps (projective contraction)
#define NSTEPS (WARM + OUTS)   // 64

typedef short bf16x8 __attribute__((ext_vector_type(8)));
typedef short bf16x4 __attribute__((ext_vector_type(4)));
typedef float f32x4  __attribute__((ext_vector_type(4)));

__device__ __forceinline__ unsigned short f2bf(float x) {  // RTE f32->bf16
    unsigned u = __float_as_uint(x);
    return (unsigned short)((u + 0x7FFFu + ((u >> 16) & 1u)) >> 16);
}
__device__ __forceinline__ float bf2f(unsigned short h) {
    return __uint_as_float(((unsigned)h) << 16);
}

// Parallel-in-time HMM forward via MFMA.
// 256 blocks x 16 chains; chain = 32 output steps + 32 warmup steps from a
// uniform guess (diag(ps)*T is a projective contraction; chain 0 re-seeded
// with exact state0). Per block-step: S_new = ps_row ⊙ (256*T @ S), T as
// bf16 hi+lo (2 MFMAs each), fp32 accum.
//
// State LDS layout: S[ks][lq][chain][8k] (k = ks*32+lq*8+e) so B-frag reads
// are stride-1 ds_read_b128 (conflict-free) and state writes are contiguous
// ds_write_b64 (conflict-free).
//
// Normalization/std: moment partials go through red[] under the SAME
// per-step barrier (parity double-buffered); unnormalized v is held in
// registers one step and written normalized during the next step.
__global__ void __launch_bounds__(512)
__attribute__((amdgpu_waves_per_eu(2, 2)))
hmm_mfma(const float* __restrict__ ps, const float* __restrict__ Tm,
         const float* __restrict__ state0, float* __restrict__ out) {
    __shared__ __align__(16) unsigned short Sbuf[2][4096];  // 2 x 8KB bf16 state
    __shared__ __align__(16) float red[2][8][NCH][4];       // [parity][wave][chain][{s,e1,e2,pad}]

    const int t    = threadIdx.x;
    const int lane = t & 63;
    const int wid  = t >> 6;      // wave 0..7 owns bins [32*wid, 32*wid+32)
    const int col  = lane & 15;   // chain index / MFMA n
    const int lq   = lane >> 4;   // k-group / C-row group
    const int blk  = blockIdx.x;
    const int binb = wid * 32;

    // ---- A-frags: T (x256) as bf16 hi/lo, resident in V/AGPRs ----
    bf16x8 Ah[2][8], Al[2][8];
    #pragma unroll
    for (int m = 0; m < 2; ++m) {
        const size_t row = (size_t)(binb + m * 16 + col);
        #pragma unroll
        for (int ks = 0; ks < 8; ++ks) {
            const float* p = Tm + row * DIM + ks * 32 + lq * 8;
            f32x4 u0 = *(const f32x4*)p;
            f32x4 u1 = *(const f32x4*)(p + 4);
            const float f[8] = {u0.x, u0.y, u0.z, u0.w, u1.x, u1.y, u1.z, u1.w};
            bf16x8 h, l;
            #pragma unroll
            for (int e = 0; e < 8; ++e) {
                const float x = f[e] * 256.0f;
                const unsigned short hs = f2bf(x);
                h[e] = (short)hs;
                l[e] = (short)f2bf(x - bf2f(hs));
            }
            Ah[m][ks] = h; Al[m][ks] = l;
        }
    }

    // ---- init buf0: all chains = uniform positive vector (scale-free) ----
    {
        bf16x8 one;
        #pragma unroll
        for (int e = 0; e < 8; ++e) one[e] = (short)0x3F80;
        *(bf16x8*)((char*)Sbuf + t * 16) = one;
    }
    __syncthreads();

    const int sbase = (blk * NCH + col) * OUTS - WARM;  // per-lane chain time base
    const int s0 = sbase < 0 ? 0 : sbase;
    f32x4 psc0 = *(const f32x4*)(ps + (size_t)s0 * DIM + binb + lq * 4);
    f32x4 psc1 = *(const f32x4*)(ps + (size_t)s0 * DIM + binb + 16 + lq * 4);

    const float bstep = 0.703125f;  // 180/256
    const float c0 = 30.0f + bstep * (float)(binb + lq * 4);

    f32x4 vh0 = {0.f, 0.f, 0.f, 0.f}, vh1 = {0.f, 0.f, 0.f, 0.f};

    for (int i = 0; i < NSTEPS; ++i) {
        const int cur = i & 1;

        if (i == WARM && blk == 0) {
            // re-seed chain 0 with the exact initial state (its warmup used
            // clamped ps[0] repeats).
            if (t < DIM) {
                const int k = t;
                char* p = (char*)Sbuf + cur * 8192 + (k >> 5) * 1024
                        + ((k >> 3) & 3) * 256 + (k & 7) * 2;
                *(unsigned short*)p = f2bf(state0[k]);
            }
            asm volatile("s_waitcnt lgkmcnt(0)" ::: "memory");
            __builtin_amdgcn_s_barrier();
            asm volatile("" ::: "memory");
        }

        // pin A-frags (forbid spill/remat)
        #pragma unroll
        for (int ks = 0; ks < 8; ++ks) {
            asm volatile("" : "+v"(Ah[0][ks]), "+v"(Ah[1][ks]),
                              "+v"(Al[0][ks]), "+v"(Al[1][ks]));
        }

        // ---- deferred output of step i-1 (partials from previous parity) ----
        if (i > WARM) {
            const int pp = cur ^ 1;
            float sumv = 0.f;
            #pragma unroll
            for (int w = 0; w < 8; ++w) sumv += red[pp][w][col][0];
            const float inv = 1.0f / sumv;
            const size_t srow = (size_t)(sbase + i - 1);
            const f32x4 o0 = vh0 * inv, o1 = vh1 * inv;
            *(f32x4*)(out + srow * DIM + binb + lq * 4) = o0;
            *(f32x4*)(out + srow * DIM + binb + 16 + lq * 4) = o1;
            if (t < NCH) {  // col == t for these lanes
                float s1 = 0.f, s2 = 0.f;
                #pragma unroll
                for (int w = 0; w < 8; ++w) {
                    s1 += red[pp][w][t][1];
                    s2 += red[pp][w][t][2];
                }
                const float m1 = s1 * inv, m2 = s2 * inv;
                const float var = m2 - m1 * m1;
                out[(size_t)NS * DIM + srow] = sqrtf(var > 0.f ? var : 0.f);
            }
        }

        // ---- B-frags: 8 stride-1 ds_read_b128 (conflict-free) ----
        const char* sbp = (const char*)Sbuf + cur * 8192;
        bf16x8 Bf[8];
        #pragma unroll
        for (int ks = 0; ks < 8; ++ks)
            Bf[ks] = *(const bf16x8*)(sbp + ks * 1024 + lane * 16);

        // prefetch next step's ps row segment (clamped)
        int snx = sbase + i + 1;
        snx = snx < 0 ? 0 : (snx > NS - 1 ? NS - 1 : snx);
        f32x4 pn0 = *(const f32x4*)(ps + (size_t)snx * DIM + binb + lq * 4);
        f32x4 pn1 = *(const f32x4*)(ps + (size_t)snx * DIM + binb + 16 + lq * 4);

        // ---- 32 MFMA: acc = (T_hi + T_lo) @ S, fp32 accum ----
        f32x4 acc0 = {0.f, 0.f, 0.f, 0.f};
        f32x4 acc1 = {0.f, 0.f, 0.f, 0.f};
        #pragma unroll
        for (int ks = 0; ks < 8; ++ks) {
            acc0 = __builtin_amdgcn_mfma_f32_16x16x32_bf16(Ah[0][ks], Bf[ks], acc0, 0, 0, 0);
            acc1 = __builtin_amdgcn_mfma_f32_16x16x32_bf16(Ah[1][ks], Bf[ks], acc1, 0, 0, 0);
            acc0 = __builtin_amdgcn_mfma_f32_16x16x32_bf16(Al[0][ks], Bf[ks], acc0, 0, 0, 0);
            acc1 = __builtin_amdgcn_mfma_f32_16x16x32_bf16(Al[1][ks], Bf[ks], acc1, 0, 0, 0);
        }

        const f32x4 v0 = acc0 * psc0;  // bins binb+lq*4+{0..3}, chain col
        const f32x4 v1 = acc1 * psc1;  // bins binb+16+lq*4+{0..3}

        // ---- next-state bf16 write: 2 contiguous ds_write_b64 ----
        {
            char* db = (char*)Sbuf + (cur ^ 1) * 8192 + wid * 1024
                     + (lq >> 1) * 256 + col * 16 + ((4 * lq) & 7) * 2;
            bf16x4 w0, w1;
            w0[0] = (short)f2bf(v0.x); w0[1] = (short)f2bf(v0.y);
            w0[2] = (short)f2bf(v0.z); w0[3] = (short)f2bf(v0.w);
            w1[0] = (short)f2bf(v1.x); w1[1] = (short)f2bf(v1.y);
            w1[2] = (short)f2bf(v1.z); w1[3] = (short)f2bf(v1.w);
            *(bf16x4*)db = w0;
            *(bf16x4*)(db + 512) = w1;  // bins +16 -> lq' += 2
        }

        // ---- moment partials (output steps), same-barrier reduction ----
        if (i >= WARM) {
            float sp = 0.f, e1 = 0.f, e2 = 0.f;
            {
                const float fv[4] = {v0.x, v0.y, v0.z, v0.w};
                #pragma unroll
                for (int j = 0; j < 4; ++j) {
                    const float b = c0 + bstep * (float)j;
                    sp += fv[j];
                    const float tb = fv[j] * b;
                    e1 += tb; e2 += tb * b;
                }
            }
            {
                const float fv[4] = {v1.x, v1.y, v1.z, v1.w};
                #pragma unroll
                for (int j = 0; j < 4; ++j) {
                    const float b = c0 + 11.25f + bstep * (float)j;
                    sp += fv[j];
                    const float tb = fv[j] * b;
                    e1 += tb; e2 += tb * b;
                }
            }
            // reduce over the 4 lq-lanes of this chain (lanes col+16k)
            sp += __shfl_xor(sp, 16); sp += __shfl_xor(sp, 32);
            e1 += __shfl_xor(e1, 16); e1 += __shfl_xor(e1, 32);
            e2 += __shfl_xor(e2, 16); e2 += __shfl_xor(e2, 32);
            if (lane < 16) {
                red[cur][wid][lane][0] = sp;
                red[cur][wid][lane][1] = e1;
                red[cur][wid][lane][2] = e2;
            }
            vh0 = v0; vh1 = v1;
        }

        // single per-step barrier (orders state + red writes); no vmcnt drain
        asm volatile("s_waitcnt lgkmcnt(0)" ::: "memory");
        __builtin_amdgcn_s_barrier();
        asm volatile("" ::: "memory");

        psc0 = pn0; psc1 = pn1;
    }

    // ---- epilogue: emit the last step's output ----
    {
        const int pp = (NSTEPS - 1) & 1;
        float sumv = 0.f;
        #pragma unroll
        for (int w = 0; w < 8; ++w) sumv += red[pp][w][col][0];
        const float inv = 1.0f / sumv;
        const size_t srow = (size_t)(sbase + NSTEPS - 1);
        const f32x4 o0 = vh0 * inv, o1 = vh1 * inv;
        *(f32x4*)(out + srow * DIM + binb + lq * 4) = o0;
        *(f32x4*)(out + srow * DIM + binb + 16 + lq * 4) = o1;
        if (t < NCH) {
            float s1 = 0.f, s2 = 0.f;
            #pragma unroll
            for (int w = 0; w < 8; ++w) {
                s1 += red[pp][w][t][1];
                s2 += red[pp][w][t][2];
            }
            const float m1 = s1 * inv, m2 = s2 * inv;
            const float var = m2 - m1 * m1;
            out[(size_t)NS * DIM + srow] = sqrtf(var > 0.f ? var : 0.f);
        }
    }
}

extern "C" void kernel_launch(void* const* d_in, const int* in_sizes, int n_in,
                              void* d_out, int out_size, void* d_ws, size_t ws_size,
                              hipStream_t stream) {
    const float* ps     = (const float*)d_in[0];
    const float* Tm     = (const float*)d_in[1];
    const float* state0 = (const float*)d_in[2];
    float* out = (float*)d_out;

    hmm_mfma<<<dim3(NS / (NCH * OUTS)), dim3(512), 0, stream>>>(ps, Tm, state0, out);
}

// Round 6
// 102.574 us; speedup vs baseline: 4.8375x; 1.0388x over previous
//
#include <hip/hip_runtime.h>
#include <math.h>

#define NS 131072
#define DIM 256
#define NCH 16                 // chains (time-chunks) per block = MFMA N
#define OUTS 16                // output steps per chain
#define WARM 24                // warmup steps (projective contraction)
#define NSTEPS (WARM + OUTS)   // 40

typedef short bf16x8 __attribute__((ext_vector_type(8)));
typedef short bf16x4 __attribute__((ext_vector_type(4)));
typedef float f32x4  __attribute__((ext_vector_type(4)));

__device__ __forceinline__ unsigned short f2bf(float x) {  // RTE f32->bf16
    unsigned u = __float_as_uint(x);
    return (unsigned short)((u + 0x7FFFu + ((u >> 16) & 1u)) >> 16);
}

// Parallel-in-time HMM forward via MFMA.
// 512 blocks (2/CU for latency overlap) x 16 chains; chain = 16 output steps
// + 24 warmup steps from a uniform guess (diag(ps)*T is a projective
// contraction; chain 0 of block 0 re-seeded with exact state0).
// Per block-step: S_new = ps_row ⊙ (256*T @ S), T as single RTE-bf16
// (state is already bf16 -- T hi/lo correction is below the noise floor),
// fp32 accum.
//
// State LDS layout: S[ks][lq][chain][8k] so B-frag reads are stride-1
// ds_read_b128 (conflict-free) and state writes contiguous ds_write_b64.
// Normalization/std: partials reduced under the SAME per-step barrier
// (parity double-buffered); unnormalized v held in regs one step, written
// normalized during the next step.
__global__ void __launch_bounds__(512)
__attribute__((amdgpu_waves_per_eu(4, 4)))   // cap ~128 regs -> 4 waves/SIMD
hmm_mfma(const float* __restrict__ ps, const float* __restrict__ Tm,
         const float* __restrict__ state0, float* __restrict__ out) {
    __shared__ __align__(16) unsigned short Sbuf[2][4096];  // 2 x 8KB bf16 state
    __shared__ __align__(16) float red[2][8][NCH][4];       // [parity][wave][chain][{s,e1,e2,pad}]

    const int t    = threadIdx.x;
    const int lane = t & 63;
    const int wid  = t >> 6;      // wave 0..7 owns bins [32*wid, 32*wid+32)
    const int col  = lane & 15;   // chain index / MFMA n
    const int lq   = lane >> 4;   // k-group / C-row group
    const int blk  = blockIdx.x;
    const int binb = wid * 32;

    // ---- A-frags: T (x256) as single bf16, resident (16 frags = 64 regs) ----
    bf16x8 Ah[2][8];
    #pragma unroll
    for (int m = 0; m < 2; ++m) {
        const size_t row = (size_t)(binb + m * 16 + col);
        #pragma unroll
        for (int ks = 0; ks < 8; ++ks) {
            const float* p = Tm + row * DIM + ks * 32 + lq * 8;
            f32x4 u0 = *(const f32x4*)p;
            f32x4 u1 = *(const f32x4*)(p + 4);
            const float f[8] = {u0.x, u0.y, u0.z, u0.w, u1.x, u1.y, u1.z, u1.w};
            bf16x8 h;
            #pragma unroll
            for (int e = 0; e < 8; ++e) h[e] = (short)f2bf(f[e] * 256.0f);
            Ah[m][ks] = h;
        }
    }

    // ---- init buf0: all chains = uniform positive vector (scale-free) ----
    {
        bf16x8 one;
        #pragma unroll
        for (int e = 0; e < 8; ++e) one[e] = (short)0x3F80;
        *(bf16x8*)((char*)Sbuf + t * 16) = one;
    }
    __syncthreads();

    const int sbase = (blk * NCH + col) * OUTS - WARM;  // per-lane chain time base
    const int s0 = sbase < 0 ? 0 : sbase;
    f32x4 psc0 = *(const f32x4*)(ps + (size_t)s0 * DIM + binb + lq * 4);
    f32x4 psc1 = *(const f32x4*)(ps + (size_t)s0 * DIM + binb + 16 + lq * 4);

    const float bstep = 0.703125f;  // 180/256
    const float c0 = 30.0f + bstep * (float)(binb + lq * 4);

    f32x4 vh0 = {0.f, 0.f, 0.f, 0.f}, vh1 = {0.f, 0.f, 0.f, 0.f};

    for (int i = 0; i < NSTEPS; ++i) {
        const int cur = i & 1;

        if (i == WARM && blk == 0) {
            // re-seed chain 0 with the exact initial state (its warmup used
            // clamped ps[0] repeats).
            if (t < DIM) {
                const int k = t;
                char* p = (char*)Sbuf + cur * 8192 + (k >> 5) * 1024
                        + ((k >> 3) & 3) * 256 + (k & 7) * 2;
                *(unsigned short*)p = f2bf(state0[k]);
            }
            asm volatile("s_waitcnt lgkmcnt(0)" ::: "memory");
            __builtin_amdgcn_s_barrier();
            asm volatile("" ::: "memory");
        }

        // pin A-frags (forbid spill/remat)
        #pragma unroll
        for (int ks = 0; ks < 8; ++ks) {
            asm volatile("" : "+v"(Ah[0][ks]), "+v"(Ah[1][ks]));
        }

        // ---- deferred output of step i-1 (partials from previous parity) ----
        if (i > WARM) {
            const int pp = cur ^ 1;
            float sumv = 0.f;
            #pragma unroll
            for (int w = 0; w < 8; ++w) sumv += red[pp][w][col][0];
            const float inv = 1.0f / sumv;
            const size_t srow = (size_t)(sbase + i - 1);
            const f32x4 o0 = vh0 * inv, o1 = vh1 * inv;
            *(f32x4*)(out + srow * DIM + binb + lq * 4) = o0;
            *(f32x4*)(out + srow * DIM + binb + 16 + lq * 4) = o1;
            if (t < NCH) {  // col == t for these lanes
                float s1 = 0.f, s2 = 0.f;
                #pragma unroll
                for (int w = 0; w < 8; ++w) {
                    s1 += red[pp][w][t][1];
                    s2 += red[pp][w][t][2];
                }
                const float m1 = s1 * inv, m2 = s2 * inv;
                const float var = m2 - m1 * m1;
                out[(size_t)NS * DIM + srow] = sqrtf(var > 0.f ? var : 0.f);
            }
        }

        // ---- B-frags: 8 stride-1 ds_read_b128 (conflict-free) ----
        const char* sbp = (const char*)Sbuf + cur * 8192;
        bf16x8 Bf[8];
        #pragma unroll
        for (int ks = 0; ks < 8; ++ks)
            Bf[ks] = *(const bf16x8*)(sbp + ks * 1024 + lane * 16);

        // prefetch next step's ps row segment (clamped)
        int snx = sbase + i + 1;
        snx = snx < 0 ? 0 : (snx > NS - 1 ? NS - 1 : snx);
        f32x4 pn0 = *(const f32x4*)(ps + (size_t)snx * DIM + binb + lq * 4);
        f32x4 pn1 = *(const f32x4*)(ps + (size_t)snx * DIM + binb + 16 + lq * 4);

        // ---- 16 MFMA: acc = T_bf16 @ S, fp32 accum ----
        f32x4 acc0 = {0.f, 0.f, 0.f, 0.f};
        f32x4 acc1 = {0.f, 0.f, 0.f, 0.f};
        #pragma unroll
        for (int ks = 0; ks < 8; ++ks) {
            acc0 = __builtin_amdgcn_mfma_f32_16x16x32_bf16(Ah[0][ks], Bf[ks], acc0, 0, 0, 0);
            acc1 = __builtin_amdgcn_mfma_f32_16x16x32_bf16(Ah[1][ks], Bf[ks], acc1, 0, 0, 0);
        }

        const f32x4 v0 = acc0 * psc0;  // bins binb+lq*4+{0..3}, chain col
        const f32x4 v1 = acc1 * psc1;  // bins binb+16+lq*4+{0..3}

        // ---- next-state bf16 write: 2 contiguous ds_write_b64 ----
        {
            char* db = (char*)Sbuf + (cur ^ 1) * 8192 + wid * 1024
                     + (lq >> 1) * 256 + col * 16 + ((4 * lq) & 7) * 2;
            bf16x4 w0, w1;
            w0[0] = (short)f2bf(v0.x); w0[1] = (short)f2bf(v0.y);
            w0[2] = (short)f2bf(v0.z); w0[3] = (short)f2bf(v0.w);
            w1[0] = (short)f2bf(v1.x); w1[1] = (short)f2bf(v1.y);
            w1[2] = (short)f2bf(v1.z); w1[3] = (short)f2bf(v1.w);
            *(bf16x4*)db = w0;
            *(bf16x4*)(db + 512) = w1;  // bins +16 -> lq' += 2
        }

        // ---- moment partials (output steps), same-barrier reduction ----
        if (i >= WARM) {
            float sp = 0.f, e1 = 0.f, e2 = 0.f;
            {
                const float fv[4] = {v0.x, v0.y, v0.z, v0.w};
                #pragma unroll
                for (int j = 0; j < 4; ++j) {
                    const float b = c0 + bstep * (float)j;
                    sp += fv[j];
                    const float tb = fv[j] * b;
                    e1 += tb; e2 += tb * b;
                }
            }
            {
                const float fv[4] = {v1.x, v1.y, v1.z, v1.w};
                #pragma unroll
                for (int j = 0; j < 4; ++j) {
                    const float b = c0 + 11.25f + bstep * (float)j;
                    sp += fv[j];
                    const float tb = fv[j] * b;
                    e1 += tb; e2 += tb * b;
                }
            }
            // reduce over the 4 lq-lanes of this chain (lanes col+16k)
            sp += __shfl_xor(sp, 16); sp += __shfl_xor(sp, 32);
            e1 += __shfl_xor(e1, 16); e1 += __shfl_xor(e1, 32);
            e2 += __shfl_xor(e2, 16); e2 += __shfl_xor(e2, 32);
            if (lane < 16) {
                red[cur][wid][lane][0] = sp;
                red[cur][wid][lane][1] = e1;
                red[cur][wid][lane][2] = e2;
            }
            vh0 = v0; vh1 = v1;
        }

        // single per-step barrier (orders state + red writes); no vmcnt drain
        asm volatile("s_waitcnt lgkmcnt(0)" ::: "memory");
        __builtin_amdgcn_s_barrier();
        asm volatile("" ::: "memory");

        psc0 = pn0; psc1 = pn1;
    }

    // ---- epilogue: emit the last step's output ----
    {
        const int pp = (NSTEPS - 1) & 1;
        float sumv = 0.f;
        #pragma unroll
        for (int w = 0; w < 8; ++w) sumv += red[pp][w][col][0];
        const float inv = 1.0f / sumv;
        const size_t srow = (size_t)(sbase + NSTEPS - 1);
        const f32x4 o0 = vh0 * inv, o1 = vh1 * inv;
        *(f32x4*)(out + srow * DIM + binb + lq * 4) = o0;
        *(f32x4*)(out + srow * DIM + binb + 16 + lq * 4) = o1;
        if (t < NCH) {
            float s1 = 0.f, s2 = 0.f;
            #pragma unroll
            for (int w = 0; w < 8; ++w) {
                s1 += red[pp][w][t][1];
                s2 += red[pp][w][t][2];
            }
            const float m1 = s1 * inv, m2 = s2 * inv;
            const float var = m2 - m1 * m1;
            out[(size_t)NS * DIM + srow] = sqrtf(var > 0.f ? var : 0.f);
        }
    }
}

extern "C" void kernel_launch(void* const* d_in, const int* in_sizes, int n_in,
                              void* d_out, int out_size, void* d_ws, size_t ws_size,
                              hipStream_t stream) {
    const float* ps     = (const float*)d_in[0];
    const float* Tm     = (const float*)d_in[1];
    const float* state0 = (const float*)d_in[2];
    float* out = (float*)d_out;

    hmm_mfma<<<dim3(NS / (NCH * OUTS)), dim3(512), 0, stream>>>(ps, Tm, state0, out);
}